// Round 7
// baseline (146.329 us; speedup 1.0000x reference)
//
#include <hip/hip_runtime.h>
#include <math.h>

#define N_BOX 4096
#define B_IMG 16
#define MAXDET 100
#define MINSZ 25.0f
#define IOUT 0.3f

// IoU with the reference's exact op order:
//   inter / (((ai + aj) - inter) + 1e-9)
// fp contract OFF so hipcc doesn't fuse wx*wy into the subtract (XLA doesn't).
__device__ __forceinline__ float iou_f(float ax1, float ay1, float ax2, float ay2, float aarea,
                                       float bx1, float by1, float bx2, float by2, float barea) {
#pragma clang fp contract(off)
    float lx = fmaxf(ax1, bx1);
    float ly = fmaxf(ay1, by1);
    float rx = fminf(ax2, bx2);
    float ry = fminf(ay2, by2);
    float wx = fmaxf(rx - lx, 0.0f);
    float wy = fmaxf(ry - ly, 0.0f);
    float inter = wx * wy;
    float denom = ((aarea + barea) - inter) + 1e-9f;
    return inter / denom;
}

// --- Kernel 1: fused key-build + stable rank + inverse-permutation write ---
// Packed key C = (orderU32(score_or_-inf) << 12) | (4095 - i); then the stable
// descending comparator (s_j>s_i || (s_j==s_i && j<i)) == single u64 '>'.
// grid: 256 blocks (16 img x 16 i-groups) x 256 threads. Block builds all 4096
// keys of its image in LDS, then each thread ranks its one box against all 4096
// via broadcast ds_read_b128 (wave-uniform address -> conflict-free).
__global__ __launch_bounds__(256) void rank_kernel(
        const float4* __restrict__ boxes, const float* __restrict__ scores,
        unsigned short* __restrict__ inv) {
    __shared__ __align__(16) unsigned long long keys[N_BOX];   // 32 KiB
    int blk = blockIdx.x;
    int b  = blk >> 4;
    int ig = blk & 15;
    int t = threadIdx.x;
    const float4* bb = boxes + (size_t)b * N_BOX;
    const float* ss = scores + (size_t)b * N_BOX;

#pragma unroll
    for (int p = 0; p < 16; ++p) {
        int j = t + 256 * p;
        float4 bx = bb[j];
        bool valid = ((bx.z - bx.x) >= MINSZ) && ((bx.w - bx.y) >= MINSZ);
        float k = valid ? ss[j] : -INFINITY;
        unsigned u = __float_as_uint(k);
        u = (u & 0x80000000u) ? ~u : (u | 0x80000000u);   // order-preserving map
        keys[j] = ((unsigned long long)u << 12) | (unsigned long long)(N_BOX - 1 - j);
    }
    __syncthreads();

    int i = ig * 256 + t;
    unsigned long long ci = keys[i];
    const ulonglong2* k2 = (const ulonglong2*)keys;
    int r = 0;
#pragma unroll 4
    for (int j2 = 0; j2 < N_BOX / 2; ++j2) {
        ulonglong2 kk = k2[j2];        // broadcast LDS read (uniform addr)
        r += (kk.x > ci) ? 1 : 0;
        r += (kk.y > ci) ? 1 : 0;
    }
    unsigned valid = (unsigned)(ci >> 43) & 1u;   // bit31 of u <=> score != -inf
    inv[b * N_BOX + r] = (unsigned short)(i | (valid << 15));
}

// --- Kernel 2: pull-based greedy NMS, one wave per image, gather via inv ---
__global__ __launch_bounds__(64) void nms_kernel(
        const float4* __restrict__ boxes, const unsigned short* __restrict__ inv,
        float* __restrict__ out) {
    __shared__ float kx1[192], ky1[192], kx2[192], ky2[192], kar[192];
    int b = blockIdx.x;
    int l = threadIdx.x;
    const float4* bb = boxes + (size_t)b * N_BOX;
    const unsigned short* iv = inv + (size_t)b * N_BOX;

    int keptCnt = 0;                    // wave-uniform
    unsigned short ni = iv[l];          // prefetch chunk 0
    float4 nbx = bb[ni & 0xFFFu];
    for (int c = 0; c < 64; ++c) {
        unsigned short e = ni;
        float4 bx = nbx;
        if (c < 63) { ni = iv[(c + 1) * 64 + l]; nbx = bb[ni & 0xFFFu]; }
        float x1 = bx.x, y1 = bx.y, x2 = bx.z, y2 = bx.w;
        float ar;
        {
#pragma clang fp contract(off)
            ar = (x2 - x1) * (y2 - y1);
        }
        bool alive = (e >> 15) != 0;
        // pull: suppress by any previously kept box (all finalized)
        for (int q = 0; q < keptCnt; ++q) {
            float v = iou_f(kx1[q], ky1[q], kx2[q], ky2[q], kar[q],
                            x1, y1, x2, y2, ar);
            if (v > IOUT) alive = false;
        }
        // intra-chunk greedy over surviving bits (ascending = greedy order)
        unsigned long long m = __ballot(alive);
        unsigned long long mm = m;
        while (mm) {
            int i = __ffsll(mm) - 1;
            float bx1 = __shfl(x1, i), by1 = __shfl(y1, i);
            float bx2 = __shfl(x2, i), by2 = __shfl(y2, i);
            float ba  = __shfl(ar, i);
            float v = iou_f(bx1, by1, bx2, by2, ba, x1, y1, x2, y2, ar);
            bool sup = (l > i) && (v > IOUT) && ((m >> l) & 1ull);
            unsigned long long sm = __ballot(sup);
            m &= ~sm;
            mm &= ~(1ull << i);
            mm &= m;
        }
        int cnt = __popcll(m);
        int pos = keptCnt + __popcll(m & ((1ull << l) - 1ull));
        if ((m >> l) & 1ull) {
            kx1[pos] = x1; ky1[pos] = y1; kx2[pos] = x2; ky2[pos] = y2; kar[pos] = ar;
        }
        keptCnt += cnt;
        __syncthreads();               // order LDS append vs next chunk's pull reads
        if (keptCnt >= MAXDET) break;
    }

    int tot = keptCnt < MAXDET ? keptCnt : MAXDET;
    float* ob = out + (size_t)b * MAXDET * 5;
    for (int r = l; r < MAXDET; r += 64) {
        float* row = ob + r * 5;
        if (r < tot) {
            row[0] = (float)b;
            row[1] = kx1[r]; row[2] = ky1[r]; row[3] = kx2[r]; row[4] = ky2[r];
        } else {
            row[0] = -1.0f;
            row[1] = 0.0f; row[2] = 0.0f; row[3] = 0.0f; row[4] = 0.0f;
        }
    }
}

extern "C" void kernel_launch(void* const* d_in, const int* in_sizes, int n_in,
                              void* d_out, int out_size, void* d_ws, size_t ws_size,
                              hipStream_t stream) {
    const float4* boxes = (const float4*)d_in[0];  // [16,4096,4] f32
    const float* scores = (const float*)d_in[1];   // [16,4096] f32
    float* out = (float*)d_out;                    // [16,100,5] f32

    // ws: inv u16 [16][4096] = 128 KiB
    unsigned short* inv = (unsigned short*)d_ws;

    rank_kernel<<<B_IMG * 16, 256, 0, stream>>>(boxes, scores, inv);
    nms_kernel<<<B_IMG, 64, 0, stream>>>(boxes, inv, out);
}

// Round 9
// 111.946 us; speedup vs baseline: 1.3071x; 1.3071x over previous
//
#include <hip/hip_runtime.h>
#include <math.h>

#define N_BOX 4096
#define B_IMG 16
#define MAXDET 100
#define MINSZ 25.0f
#define IOUT 0.3f
#define IG 16            // i-groups of 256 per image
#define JG 8             // j-groups of 512 per image
#define JW (N_BOX / JG)  // 512

// IoU with the reference's exact op order:
//   inter / (((ai + aj) - inter) + 1e-9)
// fp contract OFF so hipcc doesn't fuse wx*wy into the subtract (XLA doesn't).
__device__ __forceinline__ float iou_f(float ax1, float ay1, float ax2, float ay2, float aarea,
                                       float bx1, float by1, float bx2, float by2, float barea) {
#pragma clang fp contract(off)
    float lx = fmaxf(ax1, bx1);
    float ly = fmaxf(ay1, by1);
    float rx = fminf(ax2, bx2);
    float ry = fminf(ay2, by2);
    float wx = fmaxf(rx - lx, 0.0f);
    float wy = fmaxf(ry - ly, 0.0f);
    float inter = wx * wy;
    float denom = ((aarea + barea) - inter) + 1e-9f;
    return inter / denom;
}

// --- Kernel A: packed sort keys ---
// u = order-preserving uint of (valid ? score : -inf)  (no NaN / -0 in this data)
// C = (u << 12) | (4095 - i)  =>  stable-descending comparator == single u64 '>'
__global__ __launch_bounds__(256) void key_kernel(
        const float4* __restrict__ boxes, const float* __restrict__ scores,
        unsigned long long* __restrict__ ckey) {
    int idx = blockIdx.x * 256 + threadIdx.x;   // b*N + i
    float4 bx = boxes[idx];
    bool valid = ((bx.z - bx.x) >= MINSZ) && ((bx.w - bx.y) >= MINSZ);
    float k = valid ? scores[idx] : -INFINITY;
    unsigned u = __float_as_uint(k);
    u = (u & 0x80000000u) ? ~u : (u | 0x80000000u);
    int i = idx & (N_BOX - 1);
    ckey[idx] = ((unsigned long long)u << 12) | (unsigned long long)(N_BOX - 1 - i);
}

// --- Kernel B: partial stable ranks, 1 u64 compare per element ---
// grid: B_IMG*IG*JG = 2048 blocks x 256 threads -> 8 blocks/CU, 32 waves/CU.
// Scan address is block-uniform -> scalar SMEM loads + v_cmp_lt_u64 (VGPR=8).
__global__ __launch_bounds__(256) void partial_rank_kernel(
        const unsigned long long* __restrict__ ckey, unsigned short* __restrict__ part) {
    int blk = blockIdx.x;
    int jg = blk & (JG - 1);
    int ig = (blk >> 3) & (IG - 1);
    int b  = blk >> 7;                 // JG*IG = 128 blocks per image
    int t = threadIdx.x;
    int i = ig * 256 + t;
    unsigned long long ci = ckey[b * N_BOX + i];
    const unsigned long long* cj = ckey + b * N_BOX + jg * JW;  // wave-uniform scan
    int r = 0;
#pragma unroll 8
    for (int j = 0; j < JW; ++j)
        r += (cj[j] > ci) ? 1 : 0;
    part[(b * JG + jg) * N_BOX + i] = (unsigned short)r;
}

// --- Kernel C: sum partials -> rank; write inverse permutation (+valid bit) ---
__global__ __launch_bounds__(256) void scatter_kernel(
        const unsigned long long* __restrict__ ckey,
        const unsigned short* __restrict__ part,
        unsigned short* __restrict__ inv) {
    int idx = blockIdx.x * 256 + threadIdx.x;   // b*N + i
    int b = idx >> 12;
    int i = idx & (N_BOX - 1);
    int rank = 0;
#pragma unroll
    for (int jg = 0; jg < JG; ++jg)
        rank += part[(b * JG + jg) * N_BOX + i];
    unsigned valid = (unsigned)(ckey[idx] >> 43) & 1u;   // bit31 of u => score != -inf
    inv[b * N_BOX + rank] = (unsigned short)(i | (valid << 15));
}

// --- Kernel D: 4-wave pipelined pull-based greedy NMS, one block per image ---
// Per group of 4 chunks (64 boxes each): all 4 waves pull their chunk against
// the finalized kept list [0..K0) in parallel; then 4 barrier-separated serial
// intervals where wave s delta-pulls the kept entries appended this group and
// resolves its chunk with the intra-wave ballot greedy (ascending bit order =
// exact greedy order). Cross-wave counts go through per-interval slots scnt[s]
// (fresh address per interval -> no same-interval read/write races).
__global__ __launch_bounds__(256) void nms_kernel(
        const float4* __restrict__ boxes, const unsigned short* __restrict__ inv,
        float* __restrict__ out) {
    __shared__ __align__(16) float4 kbox[384];   // kept boxes, rank order (max 99+256)
    __shared__ int scnt[4];                      // per-interval kept increments
    int b = blockIdx.x;
    int t = threadIdx.x;
    int w = t >> 6, l = t & 63;
    const float4* bb = boxes + (size_t)b * N_BOX;
    const unsigned short* iv = inv + (size_t)b * N_BOX;

    int kept = 0;                                // block-uniform at group boundaries
    for (int g = 0; g < 16; ++g) {
        int c = g * 4 + w;                       // this wave's chunk
        unsigned short e = iv[c * 64 + l];
        float4 bx = bb[e & 0xFFFu];
        float x1 = bx.x, y1 = bx.y, x2 = bx.z, y2 = bx.w;
        float ar;
        {
#pragma clang fp contract(off)
            ar = (x2 - x1) * (y2 - y1);
        }
        bool alive = (e >> 15) != 0;
        int K0 = kept;
        // phase 1 (parallel across 4 waves): pull vs finalized kept [0..K0)
        for (int q = 0; q < K0; ++q) {
            float4 kb = kbox[q];                 // uniform-addr broadcast read
            float kar;
            {
#pragma clang fp contract(off)
                kar = (kb.z - kb.x) * (kb.w - kb.y);
            }
            float v = iou_f(kb.x, kb.y, kb.z, kb.w, kar, x1, y1, x2, y2, ar);
            if (v > IOUT) alive = false;
        }
        // phase 2: serial resolve intervals
        for (int s = 0; s < 4; ++s) {
            if (w == s) {
                int Kcur = K0;
                for (int ss = 0; ss < s; ++ss) Kcur += scnt[ss];  // written in earlier intervals
                int cnt = 0;
                if (Kcur < MAXDET) {
                    // delta pull vs kept appended this group [K0..Kcur)
                    for (int q = K0; q < Kcur; ++q) {
                        float4 kb = kbox[q];
                        float kar;
                        {
#pragma clang fp contract(off)
                            kar = (kb.z - kb.x) * (kb.w - kb.y);
                        }
                        float v = iou_f(kb.x, kb.y, kb.z, kb.w, kar, x1, y1, x2, y2, ar);
                        if (v > IOUT) alive = false;
                    }
                    // intra-chunk greedy over surviving bits (ascending = greedy order)
                    unsigned long long m = __ballot(alive);
                    unsigned long long mm = m;
                    while (mm) {
                        int i = __ffsll(mm) - 1;
                        float bx1 = __shfl(x1, i), by1 = __shfl(y1, i);
                        float bx2 = __shfl(x2, i), by2 = __shfl(y2, i);
                        float ba  = __shfl(ar, i);
                        float v = iou_f(bx1, by1, bx2, by2, ba, x1, y1, x2, y2, ar);
                        bool sup = (l > i) && (v > IOUT) && ((m >> l) & 1ull);
                        unsigned long long sm = __ballot(sup);
                        m &= ~sm;
                        mm &= ~(1ull << i);
                        mm &= m;
                    }
                    cnt = __popcll(m);
                    int pos = Kcur + __popcll(m & ((1ull << l) - 1ull));
                    if ((m >> l) & 1ull) kbox[pos] = make_float4(x1, y1, x2, y2);
                }
                if (l == 0) scnt[s] = cnt;
            }
            __syncthreads();                     // publish kbox appends + scnt[s]
        }
        kept = K0 + scnt[0] + scnt[1] + scnt[2] + scnt[3];
        __syncthreads();                         // protect scnt reads from next group's writes
        if (kept >= MAXDET) break;               // uniform; kept list prefix-exact
    }

    int tot = kept < MAXDET ? kept : MAXDET;
    float* ob = out + (size_t)b * MAXDET * 5;
    for (int r = t; r < MAXDET; r += 256) {
        float* row = ob + r * 5;
        if (r < tot) {
            float4 kb = kbox[r];
            row[0] = (float)b;
            row[1] = kb.x; row[2] = kb.y; row[3] = kb.z; row[4] = kb.w;
        } else {
            row[0] = -1.0f;
            row[1] = 0.0f; row[2] = 0.0f; row[3] = 0.0f; row[4] = 0.0f;
        }
    }
}

extern "C" void kernel_launch(void* const* d_in, const int* in_sizes, int n_in,
                              void* d_out, int out_size, void* d_ws, size_t ws_size,
                              hipStream_t stream) {
    const float4* boxes = (const float4*)d_in[0];  // [16,4096,4] f32
    const float* scores = (const float*)d_in[1];   // [16,4096] f32
    float* out = (float*)d_out;                    // [16,100,5] f32

    // ws layout (1.625 MiB):
    //   ckey u64 [0, 512K) | part u16 [512K, 1536K) | inv u16 [1536K, 1664K)
    unsigned long long* ckey = (unsigned long long*)d_ws;
    unsigned short* part     = (unsigned short*)((char*)d_ws + (size_t)524288);
    unsigned short* inv      = (unsigned short*)((char*)d_ws + (size_t)1572864);

    key_kernel<<<B_IMG * N_BOX / 256, 256, 0, stream>>>(boxes, scores, ckey);
    partial_rank_kernel<<<B_IMG * IG * JG, 256, 0, stream>>>(ckey, part);
    scatter_kernel<<<B_IMG * N_BOX / 256, 256, 0, stream>>>(ckey, part, inv);
    nms_kernel<<<B_IMG, 256, 0, stream>>>(boxes, inv, out);
}